// Round 1
// baseline (561.545 us; speedup 1.0000x reference)
//
#include <hip/hip_runtime.h>
#include <stdint.h>

// Viterbi CRF decode: B=1024, T=1024, N=34 (32 tags + START=32 + END=33)
#define BB 1024
#define TT 1024
#define NN 34
#define NP 36            // padded state dim in LDS score buffers (144B rows, 16B-aligned)
#define NB 2             // batches per block
#define TPB (NB * 136)   // 272 threads = 2 batches x (34 j x 4 h)
#define NEGV -6969.0f
#define PADV -1.0e30f

template<int C>
__device__ __forceinline__ int dpp_i(int x) {
    return __builtin_amdgcn_update_dpp(0, x, C, 0xF, 0xF, true);
}
template<int C>
__device__ __forceinline__ float dpp_f(float x) {
    return __int_as_float(dpp_i<C>(__float_as_int(x)));
}

// Barrier that drains LDS (lgkmcnt) only: global prefetch loads stay in
// flight across steps (plain __syncthreads would force vmcnt(0) -> exposes
// full HBM latency on the critical path every step).
__device__ __forceinline__ void lds_barrier() {
    asm volatile("s_waitcnt lgkmcnt(0)\n\ts_barrier" ::: "memory");
}

__device__ __forceinline__ int imin2(int a, int b) { return a < b ? a : b; }

__global__ __launch_bounds__(TPB, 3) void viterbi_full(
        const float* __restrict__ feat,   // [B,T,34]
        const float* __restrict__ trans,  // [34,34]
        unsigned char* __restrict__ bpg,  // workspace [B,T,34] backpointers
        float* __restrict__ out)          // best[B] ++ path[B,T+1]
{
    __shared__ __align__(16) float sbuf[2][NB][NP];   // ping-pong score buffers
    __shared__ float fsb[NB][NN];
    __shared__ unsigned char Fm[NB][16][NN];
    __shared__ int Eb[NB][16];
    __shared__ int idxs[NB];

    const int tid = threadIdx.x;
    const int bl  = (tid >= 136) ? 1 : 0;
    const int r   = tid - bl * 136;
    const int j   = r >> 2;          // 0..33 target state
    const int h   = r & 3;           // k-window quarter; quads aligned (136%4==0)
    const int kw  = h << 3;          // window start: 0,8,16,24 -> 10 states each
                                     // (windows overlap; dups harmless for max +
                                     //  min-index argmax; every window 16B-aligned)
    const int bg  = blockIdx.x * NB + bl;

    // ---- init LDS score buffers (pads -1e30; init scores: START=0, else NEG)
    for (int e = tid; e < 2 * NB * NP; e += TPB) {
        int kk = e % NP;
        ((float*)sbuf)[e] = (kk >= NN) ? PADV : ((kk == 32) ? 0.0f : NEGV);
    }

    // ---- per-thread constants in registers (10 transitions for this window)
    float tr[10];
#pragma unroll
    for (int i = 0; i < 10; ++i) tr[i] = trans[j * NN + kw + i];
    const float trE = (r < NN) ? trans[33 * NN + r] : 0.0f;

    const float* fp = feat + (size_t)bg * TT * NN + j;
    unsigned char* bpt = bpg + (size_t)bg * TT * NN + j;

    // 4-deep feature prefetch ring (t = 0..3)
    float fr0 = fp[0 * NN], fr1 = fp[1 * NN], fr2 = fp[2 * NN], fr3 = fp[3 * NN];

    float* const s0 = &sbuf[0][bl][0];
    float* const s1 = &sbuf[1][bl][0];

    // deferred-argmax state: previous step's window values + reduced max + bp dst.
    // Step 0 stores one garbage byte to bp[t=0]; step 1 overwrites it in
    // program order (same thread, same address) with the real value.
    float pvv[10];
#pragma unroll
    for (int i = 0; i < 10; ++i) pvv[i] = 0.0f;
    float pm = -1.0e30f;
    unsigned char* pbp = bpt;

    __syncthreads();

    // previous step's argmax (registers only -> runs in the LDS-read shadow)
    auto amax_flush = [&]() {
        int e[10];
#pragma unroll
        for (int i = 0; i < 10; ++i) e[i] = (pvv[i] == pm) ? (kw + i) : 127;
        int a0 = imin2(e[0], e[1]), a1 = imin2(e[2], e[3]);
        int a2 = imin2(e[4], e[5]), a3 = imin2(e[6], e[7]);
        int a4 = imin2(e[8], e[9]);
        int am = imin2(imin2(imin2(a0, a1), imin2(a2, a3)), a4);
        int ao = dpp_i<0xB1>(am); am = imin2(ao, am);   // quad xor 1
        ao = dpp_i<0x4E>(am);     am = imin2(ao, am);   // quad xor 2
        if (h == 0) *pbp = (unsigned char)am;
    };

    // one Viterbi step: phase A issue aligned LDS reads; phase B previous
    // argmax + bp store (hides read latency); phase C max + write + barrier.
    // exact fp order (s+f)+t; argmax = first index attaining max.
    auto vstep = [&](const float* __restrict__ srd, float* __restrict__ swr,
                     float fv, unsigned char* bpw) {
        // A: 10 window floats via b128+b128+b64 (16B-aligned, conflict-free)
        const float4 va = *reinterpret_cast<const float4*>(srd + kw);
        const float4 vb = *reinterpret_cast<const float4*>(srd + kw + 4);
        const float2 vc = *reinterpret_cast<const float2*>(srd + kw + 8);
        // B: previous step's argmax while reads are in flight
        amax_flush();
        // C: scores for this step
        float sv[10];
        sv[0] = va.x; sv[1] = va.y; sv[2] = va.z; sv[3] = va.w;
        sv[4] = vb.x; sv[5] = vb.y; sv[6] = vb.z; sv[7] = vb.w;
        sv[8] = vc.x; sv[9] = vc.y;
        float vv[10];
#pragma unroll
        for (int i = 0; i < 10; ++i) vv[i] = (sv[i] + fv) + tr[i];
        float t0 = fmaxf(vv[0], vv[1]), t1 = fmaxf(vv[2], vv[3]);
        float t2 = fmaxf(vv[4], vv[5]), t3 = fmaxf(vv[6], vv[7]);
        float t4 = fmaxf(vv[8], vv[9]);
        float m = fmaxf(fmaxf(fmaxf(t0, t1), fmaxf(t2, t3)), t4);
        m = fmaxf(m, dpp_f<0xB1>(m));   // quad_perm(1,0,3,2): xor 1
        m = fmaxf(m, dpp_f<0x4E>(m));   // quad_perm(2,3,0,1): xor 2
        if (h == 0) swr[j] = m;
#pragma unroll
        for (int i = 0; i < 10; ++i) pvv[i] = vv[i];
        pm = m;
        pbp = bpw;
        lds_barrier();
    };

    // ---- forward: 255 iters x 4 steps (prefetch t+4) + 4-step epilogue
    for (int n = 0; n < 255; ++n) {
        { float f = fr0; fr0 = fp[4 * NN]; vstep(s0, s1, f, bpt + 0 * NN); }
        { float f = fr1; fr1 = fp[5 * NN]; vstep(s1, s0, f, bpt + 1 * NN); }
        { float f = fr2; fr2 = fp[6 * NN]; vstep(s0, s1, f, bpt + 2 * NN); }
        { float f = fr3; fr3 = fp[7 * NN]; vstep(s1, s0, f, bpt + 3 * NN); }
        fp += 4 * NN; bpt += 4 * NN;
    }
    vstep(s0, s1, fr0, bpt + 0 * NN);
    vstep(s1, s0, fr1, bpt + 1 * NN);
    vstep(s0, s1, fr2, bpt + 2 * NN);
    vstep(s1, s0, fr3, bpt + 3 * NN);
    amax_flush();                      // bp for t=1023
    // final scores (t=1024 even) live in sbuf[0]

    // ---- end transition + final argmax
    if (r < NN) fsb[bl][r] = s0[r] + trE;
    __syncthreads();   // also drains vmcnt: all bp stores of this wave done
    if (r == 0) {
        float bm = fsb[bl][0]; int bi = 0;
        for (int k = 1; k < NN; ++k) {
            float v = fsb[bl][k];
            if (v > bm) { bm = v; bi = k; }
        }
        out[bg] = bm; idxs[bl] = bi;
    }
    __syncthreads();

    // ---- backtrack on this block's own bp (L2-resident, same CU/XCD)
    const unsigned char* __restrict__ bb = bpg + (size_t)bg * TT * NN;

    // level-1: 16 chunks x 64 steps x 34 hypotheses; 136 thr x 4 jobs (ILP)
    {
        int g = (r >= 102) ? 3 : ((r >= 68) ? 2 : ((r >= 34) ? 1 : 0));
        int x = r - 34 * g;
        int c0 = g, c1 = g + 4, c2 = g + 8, c3 = g + 12;
        int m0 = x, m1 = x, m2 = x, m3 = x;
        for (int i = 63; i >= 0; --i) {
            m0 = bb[(size_t)((c0 * 64 + i) * NN) + m0];
            m1 = bb[(size_t)((c1 * 64 + i) * NN) + m1];
            m2 = bb[(size_t)((c2 * 64 + i) * NN) + m2];
            m3 = bb[(size_t)((c3 * 64 + i) * NN) + m3];
        }
        Fm[bl][c0][x] = m0; Fm[bl][c1][x] = m1;
        Fm[bl][c2][x] = m2; Fm[bl][c3][x] = m3;
    }
    __syncthreads();

    // level-2: serial 16-chunk scan
    if (r == 0) {
        int e = idxs[bl];
        Eb[bl][15] = e;
        for (int c = 15; c >= 1; --c) { e = Fm[bl][c][e]; Eb[bl][c - 1] = e; }
    }
    __syncthreads();

    // emit: winning hypothesis per chunk re-chases and writes the path
    float* po = out + BB + (size_t)bg * (TT + 1);
    if (r < 16) {
        int c = r;
        int m = Eb[bl][c];
        for (int i = 63; i >= 0; --i) {
            m = bb[(size_t)((c * 64 + i) * NN) + m];
            po[c * 64 + i] = (float)m;
        }
    }
    if (r == 16) po[TT] = (float)idxs[bl];
}

extern "C" void kernel_launch(void* const* d_in, const int* in_sizes, int n_in,
                              void* d_out, int out_size, void* d_ws, size_t ws_size,
                              hipStream_t stream) {
    const float* feat  = (const float*)d_in[0];   // [1024,1024,34]
    const float* trans = (const float*)d_in[1];   // [34,34]
    float* out = (float*)d_out;                   // 1024 + 1024*1025 floats
    unsigned char* bp = (unsigned char*)d_ws;     // 35,651,584 B backpointers

    viterbi_full<<<BB / NB, TPB, 0, stream>>>(feat, trans, bp, out);
}